// Round 3
// baseline (269.211 us; speedup 1.0000x reference)
//
#include <hip/hip_runtime.h>

// DenseCRF-RNN fwd, D=64,H=128,W=128, L=2, 5 iters.
// 2-label reduction: track q1 = sigmoid(cur1-cur0) only.
// Per iter: delta = P - Ac*blur3d(q) - M*num(q),  q_new = sigmoid(delta)
//   num(q) = q(x) + sum_{13 fwd dirs d} [ Wd(x) q(x+d) + Wd(x-d) q(x-d) ]
//   (weight symmetry: w(x,x+d) = w(x+d,x); Wd(x) = w(I(x),I(x+d)) fp16).
//   M  = Bc/den(x),  P = dU - Ksp*blurOnes - Kbl*bilatOnes  (all img-only,
//   precomputed once; weights constant across CRF iterations).
// R2 bug: forward weight was loaded at g+OFF; must be at g (center). Fixed.
// ws: qA[N] qB[N] P[N] M[N] f32 | guardLo[G] W[13N] guardHi[G] fp16 (~42 MB).

#define DD 64
#define HH 128
#define WW 128
#define NN (DD*HH*WW)   // 1048576
#define GUARD 16520     // > 16384+128+1+3+4

typedef _Float16 hf;
typedef _Float16 hf4 __attribute__((ext_vector_type(4)));

__device__ __forceinline__ float bfac(int p, int dim) {
    const float K[5] = {0.05448868f, 0.24420134f, 0.40261995f, 0.24420134f, 0.05448868f};
    float s = 0.f;
#pragma unroll
    for (int o = -2; o <= 2; ++o) {
        int pp = p + o;
        s += (pp >= 0 && pp < dim) ? K[o + 2] : 0.f;
    }
    return s;
}

__global__ __launch_bounds__(256) void crf_pre(
    const float* __restrict__ img, const float* __restrict__ h,
    const float* __restrict__ f1, const float* __restrict__ w0,
    const float* __restrict__ sw, const float* __restrict__ bw,
    const float* __restrict__ cm,
    float* __restrict__ qA, float* __restrict__ P,
    float* __restrict__ M, hf* __restrict__ W)
{
    const float Sc[4] = {1.f, 0.80073740f, 0.64118039f, 0.51341712f};
    int g = blockIdx.x * 256 + threadIdx.x;
    if (g >= NN) return;
    if (g < GUARD) {            // zero guard zones around the weight planes
        W[-1 - g] = (hf)0.f;
        W[13 * NN + g] = (hf)0.f;
    }
    int z = g >> 14, rem = g & 16383, y = rem >> 7, x = rem & 127;

    float cd0 = cm[2] - cm[0], cd1 = cm[3] - cm[1];
    float Ksp = cd0 * sw[0] + cd1 * sw[2];
    float Kbl = cd0 * bw[0] + cd1 * bw[2];
    float Bc  = cd0 * (bw[1] - bw[0]) + cd1 * (bw[3] - bw[2]);

    float Ic = img[g];
    float h0 = h[g], h1 = h[NN + g], fv = f1[g];
    float logp = -0.5f * Ic * Ic - 0.91893853320467274f;   // N(0,1) logpdf
    float t = -(w0[0] + logp - fv);
    float bones = bfac(z, DD) * bfac(y, HH) * bfac(x, WW);

    float den = 0.f, numi = 0.f;
    int o = 0;
#pragma unroll
    for (int dz = -1; dz <= 1; ++dz)
#pragma unroll
        for (int dy = -1; dy <= 1; ++dy)
#pragma unroll
            for (int dx = -1; dx <= 1; ++dx) {
                int nz = z + dz, ny = y + dy, nx = x + dx;
                bool inb = (unsigned)nz < 64u && (unsigned)ny < 128u && (unsigned)nx < 128u;
                float In = inb ? img[g + dz * 16384 + dy * 128 + dx] : 0.f;
                float dd = Ic - In;
                float w = Sc[dz * dz + dy * dy + dx * dx] * __expf(-2.f * dd * dd);
                den += w;
                numi += inb ? w : 0.f;
                if (o >= 14) W[(o - 14) * NN + g] = (hf)w;   // 13 forward planes
                ++o;
            }
    float dq = h1 - h0;
    qA[g] = 1.f / (1.f + __expf(-dq));                 // q after softmax(logits)
    M[g]  = Bc / den;
    P[g]  = dq * t - Ksp * bones - Kbl * (numi / den);
}

__device__ __forceinline__ void ldrow(const float* p, float* r) {
    float4 a = *(const float4*)p;
    float4 b = *(const float4*)(p + 4);
    r[0] = a.x; r[1] = a.y; r[2] = a.z; r[3] = a.w;
    r[4] = b.x; r[5] = b.y; r[6] = b.z; r[7] = b.w;
}

// load 4 fp16 weights at plane offset g+OFF; SH = ((-OFF%4)+4)%4 keeps the
// hf4 vector loads 8B-aligned (g%4==0), extracts are compile-time.
template <int OFF, int SH>
__device__ __forceinline__ void loadw4(const hf* __restrict__ base, int g, float* w) {
    const hf4* p = (const hf4*)(base + (g + OFF - SH));
    hf4 a = p[0];
    if constexpr (SH == 0) {
        w[0] = (float)a.x; w[1] = (float)a.y; w[2] = (float)a.z; w[3] = (float)a.w;
    } else {
        hf4 b = p[1];
#pragma unroll
        for (int xi = 0; xi < 4; ++xi) {
            constexpr int S = SH;
            int k = S + xi;
            w[xi] = (k < 4) ? (float)a[k] : (float)b[k - 4];
        }
    }
}

template <int FD, int DZ, int DY, int DX>
__device__ __forceinline__ void dir_acc(const hf* __restrict__ W, int g,
                                        const float* rp, const float* rm, float* num) {
    constexpr int OFF = DZ * 16384 + DY * 128 + DX;
    constexpr int SB = (((-DX) % 4) + 4) % 4;
    float wf[4], wb[4];
    loadw4<0, 0>(W + FD * NN, g, wf);       // forward weight lives at center
    loadw4<-OFF, SB>(W + FD * NN, g, wb);   // backward weight lives at x-d
#pragma unroll
    for (int xi = 0; xi < 4; ++xi)
        num[xi] += wf[xi] * rp[2 + xi + DX] + wb[xi] * rm[2 + xi - DX];
}

// Tile: 8(z) x 8(y) x 16(x) outputs per block, 256 threads, 4 x-voxels/thread.
template <bool LAST>
__global__ __launch_bounds__(256) void crf_iter(
    const float* __restrict__ qsrc, float* __restrict__ qdst,
    const float* __restrict__ P, const float* __restrict__ M,
    const hf* __restrict__ W,
    const float* __restrict__ sw, const float* __restrict__ cm,
    const float* __restrict__ f1, float* __restrict__ out)
{
    const float K0 = 0.05448868f, K1 = 0.24420134f, K2 = 0.40261995f;

    __shared__ float qs[12][12][20];   // q tile, halo 2
    __shared__ float t1[12][12][16];   // blur-x
    __shared__ float t2[12][8][16];    // blur-xy

    const int tid = threadIdx.x;
    const int x0 = blockIdx.x * 16, y0 = blockIdx.y * 8, zB = blockIdx.z * 8;

    const float cd0 = cm[2] - cm[0], cd1 = cm[3] - cm[1];
    const float Ac = cd0 * (sw[1] - sw[0]) + cd1 * (sw[3] - sw[2]);

    float* qf = &qs[0][0][0];
    for (int idx = tid; idx < 2880; idx += 256) {
        int lz = idx / 240, r = idx - lz * 240, ly = r / 20, lx2 = r - ly * 20;
        int gz = zB + lz - 2, gy = y0 + ly - 2, gx = x0 + lx2 - 2;
        float v = 0.f;
        if ((unsigned)gz < 64u && (unsigned)gy < 128u && (unsigned)gx < 128u)
            v = qsrc[(gz << 14) + (gy << 7) + gx];
        qf[idx] = v;
    }
    __syncthreads();

    // blur along x
    for (int idx = tid; idx < 576; idx += 256) {
        int lz = idx / 48, r = idx - lz * 48, ly = r / 4, c4 = (r - ly * 4) * 4;
        const float* row = &qs[lz][ly][c4];
        float4 a = *(const float4*)row;
        float4 b = *(const float4*)(row + 4);
        float4 o;
        o.x = K0 * (a.x + b.x) + K1 * (a.y + a.w) + K2 * a.z;
        o.y = K0 * (a.y + b.y) + K1 * (a.z + b.x) + K2 * a.w;
        o.z = K0 * (a.z + b.z) + K1 * (a.w + b.y) + K2 * b.x;
        o.w = K0 * (a.w + b.w) + K1 * (b.x + b.z) + K2 * b.y;
        *(float4*)&t1[lz][ly][c4] = o;
    }
    __syncthreads();

    // blur along y
    for (int idx = tid; idx < 384; idx += 256) {
        int lz = idx / 32, r = idx - lz * 32, ly = r / 4, c4 = (r - ly * 4) * 4;
        float4 r0 = *(const float4*)&t1[lz][ly][c4];
        float4 r1 = *(const float4*)&t1[lz][ly + 1][c4];
        float4 r2 = *(const float4*)&t1[lz][ly + 2][c4];
        float4 r3 = *(const float4*)&t1[lz][ly + 3][c4];
        float4 r4 = *(const float4*)&t1[lz][ly + 4][c4];
        float4 o;
        o.x = K0 * (r0.x + r4.x) + K1 * (r1.x + r3.x) + K2 * r2.x;
        o.y = K0 * (r0.y + r4.y) + K1 * (r1.y + r3.y) + K2 * r2.y;
        o.z = K0 * (r0.z + r4.z) + K1 * (r1.z + r3.z) + K2 * r2.z;
        o.w = K0 * (r0.w + r4.w) + K1 * (r1.w + r3.w) + K2 * r2.w;
        *(float4*)&t2[lz][ly][c4] = o;
    }
    __syncthreads();

    const int lx = (tid & 3) * 4;
    const int ly = (tid >> 2) & 7;
    const int lz = tid >> 5;

    // blur along z (final spatial message)
    float4 za = *(const float4*)&t2[lz][ly][lx];
    float4 zb = *(const float4*)&t2[lz + 1][ly][lx];
    float4 zc = *(const float4*)&t2[lz + 2][ly][lx];
    float4 zd = *(const float4*)&t2[lz + 3][ly][lx];
    float4 ze = *(const float4*)&t2[lz + 4][ly][lx];
    float sp[4];
    sp[0] = K0 * (za.x + ze.x) + K1 * (zb.x + zd.x) + K2 * zc.x;
    sp[1] = K0 * (za.y + ze.y) + K1 * (zb.y + zd.y) + K2 * zc.y;
    sp[2] = K0 * (za.z + ze.z) + K1 * (zb.z + zd.z) + K2 * zc.z;
    sp[3] = K0 * (za.w + ze.w) + K1 * (zb.w + zd.w) + K2 * zc.w;

    const int g = ((zB + lz) << 14) + ((y0 + ly) << 7) + (x0 + lx);

    // bilateral: center + 13 symmetric direction pairs, weights from fp16 planes
    float num[4];
    float rc[8], rp[8], rm[8];
    ldrow(&qs[lz + 2][ly + 2][lx], rc);
#pragma unroll
    for (int xi = 0; xi < 4; ++xi) num[xi] = rc[2 + xi];

    dir_acc<0, 0, 0, 1>(W, g, rc, rc, num);

    ldrow(&qs[lz + 2][ly + 3][lx], rp);
    ldrow(&qs[lz + 2][ly + 1][lx], rm);
    dir_acc<1, 0, 1, -1>(W, g, rp, rm, num);
    dir_acc<2, 0, 1, 0>(W, g, rp, rm, num);
    dir_acc<3, 0, 1, 1>(W, g, rp, rm, num);

    ldrow(&qs[lz + 3][ly + 1][lx], rp);
    ldrow(&qs[lz + 1][ly + 3][lx], rm);
    dir_acc<4, 1, -1, -1>(W, g, rp, rm, num);
    dir_acc<5, 1, -1, 0>(W, g, rp, rm, num);
    dir_acc<6, 1, -1, 1>(W, g, rp, rm, num);

    ldrow(&qs[lz + 3][ly + 2][lx], rp);
    ldrow(&qs[lz + 1][ly + 2][lx], rm);
    dir_acc<7, 1, 0, -1>(W, g, rp, rm, num);
    dir_acc<8, 1, 0, 0>(W, g, rp, rm, num);
    dir_acc<9, 1, 0, 1>(W, g, rp, rm, num);

    ldrow(&qs[lz + 3][ly + 3][lx], rp);
    ldrow(&qs[lz + 1][ly + 1][lx], rm);
    dir_acc<10, 1, 1, -1>(W, g, rp, rm, num);
    dir_acc<11, 1, 1, 0>(W, g, rp, rm, num);
    dir_acc<12, 1, 1, 1>(W, g, rp, rm, num);

    float4 Pv = *(const float4*)&P[g];
    float4 Mv = *(const float4*)&M[g];
    float pr[4] = {Pv.x, Pv.y, Pv.z, Pv.w};
    float mv[4] = {Mv.x, Mv.y, Mv.z, Mv.w};
    float qn[4];
#pragma unroll
    for (int xi = 0; xi < 4; ++xi) {
        float dn = pr[xi] - Ac * sp[xi] - mv[xi] * num[xi];
        qn[xi] = 1.f / (1.f + __expf(-dn));
    }

    if (!LAST) {
        float4 o = {qn[0], qn[1], qn[2], qn[3]};
        *(float4*)&qdst[g] = o;
    } else {
        float4 o1 = {qn[0], qn[1], qn[2], qn[3]};
        float4 o0 = {1.f - qn[0], 1.f - qn[1], 1.f - qn[2], 1.f - qn[3]};
        *(float4*)&out[g] = o0;
        *(float4*)&out[NN + g] = o1;
        float4 fv = *(const float4*)&f1[g];
        *(float4*)&out[2 * NN + g] = fv;
    }
}

extern "C" void kernel_launch(void* const* d_in, const int* in_sizes, int n_in,
                              void* d_out, int out_size, void* d_ws, size_t ws_size,
                              hipStream_t stream)
{
    const float* img = (const float*)d_in[0];
    const float* h   = (const float*)d_in[1];
    const float* f1  = (const float*)d_in[2];
    const float* w0  = (const float*)d_in[3];
    const float* sw  = (const float*)d_in[4];
    const float* bw  = (const float*)d_in[5];
    const float* cm  = (const float*)d_in[6];
    float* out = (float*)d_out;

    float* qA = (float*)d_ws;
    float* qB = qA + NN;
    float* P  = qB + NN;
    float* M  = P + NN;
    hf* W = (hf*)(M + NN) + GUARD;   // guardLo | 13 planes | guardHi

    crf_pre<<<NN / 256, 256, 0, stream>>>(img, h, f1, w0, sw, bw, cm, qA, P, M, W);

    dim3 grid(WW / 16, HH / 8, DD / 8);   // 1024 blocks
    crf_iter<false><<<grid, 256, 0, stream>>>(qA, qB, P, M, W, sw, cm, nullptr, nullptr);
    crf_iter<false><<<grid, 256, 0, stream>>>(qB, qA, P, M, W, sw, cm, nullptr, nullptr);
    crf_iter<false><<<grid, 256, 0, stream>>>(qA, qB, P, M, W, sw, cm, nullptr, nullptr);
    crf_iter<false><<<grid, 256, 0, stream>>>(qB, qA, P, M, W, sw, cm, nullptr, nullptr);
    crf_iter<true ><<<grid, 256, 0, stream>>>(qA, nullptr, P, M, W, sw, cm, f1, out);
}

// Round 5
// 238.199 us; speedup vs baseline: 1.1302x; 1.1302x over previous
//
#include <hip/hip_runtime.h>

// DenseCRF-RNN fwd, D=64,H=128,W=128, L=2, 5 iters.
// 2-label reduction: track q1 = sigmoid(cur1-cur0) only.
// Per iter: delta = P - Ac*blur3d(q) - M*num(q),  q_new = sigmoid(delta)
//   num(q) = sum_{27 dirs o} W_o(x) * q(x+d_o)   (center weight = 1)
//   M = Bc/den(x),  P = dU - Ksp*blurOnes - Kbl*bilatOnes  (img-only, precomputed).
// R3 lesson: 13 fp16 planes at 2-MiB (pow2) stride alias L2 sets -> thrash.
// R4: AoS weights W[chunk=g/4][27][4] fp16, record stride 224 B (non-pow2,
// all reads at center, contiguous 216 B/thread); qA/qB/P/M staggered +264 f.
// ws: qA | qB | P | M (f32, NN+264 apart) | W (58.7 MB)  ~75 MB total.

#define DD 64
#define HH 128
#define WW 128
#define NN (DD*HH*WW)   // 1048576
#define PAD 264
#define RSTRIDE 112     // hf per 4-voxel record: 27*4=108, padded to 112 (224 B)

typedef _Float16 hf;
typedef _Float16 hf4 __attribute__((ext_vector_type(4)));

__device__ __forceinline__ float bfac(int p, int dim) {
    const float K[5] = {0.05448868f, 0.24420134f, 0.40261995f, 0.24420134f, 0.05448868f};
    float s = 0.f;
#pragma unroll
    for (int o = -2; o <= 2; ++o) {
        int pp = p + o;
        s += (pp >= 0 && pp < dim) ? K[o + 2] : 0.f;
    }
    return s;
}

__global__ __launch_bounds__(256) void crf_pre(
    const float* __restrict__ img, const float* __restrict__ h,
    const float* __restrict__ f1, const float* __restrict__ w0,
    const float* __restrict__ sw, const float* __restrict__ bw,
    const float* __restrict__ cm,
    float* __restrict__ qA, float* __restrict__ P,
    float* __restrict__ M, hf* __restrict__ W)
{
    const float Sc[4] = {1.f, 0.80073740f, 0.64118039f, 0.51341712f};
    int g = blockIdx.x * 256 + threadIdx.x;
    if (g >= NN) return;
    int z = g >> 14, rem = g & 16383, y = rem >> 7, x = rem & 127;

    float cd0 = cm[2] - cm[0], cd1 = cm[3] - cm[1];
    float Ksp = cd0 * sw[0] + cd1 * sw[2];
    float Kbl = cd0 * bw[0] + cd1 * bw[2];
    float Bc  = cd0 * (bw[1] - bw[0]) + cd1 * (bw[3] - bw[2]);

    float Ic = img[g];
    float h0 = h[g], h1 = h[NN + g], fv = f1[g];
    float logp = -0.5f * Ic * Ic - 0.91893853320467274f;   // N(0,1) logpdf
    float t = -(w0[0] + logp - fv);
    float bones = bfac(z, DD) * bfac(y, HH) * bfac(x, WW);

    hf* rec = W + (g >> 2) * RSTRIDE + (g & 3);

    float den = 0.f, numi = 0.f;
    int o = 0;
#pragma unroll
    for (int dz = -1; dz <= 1; ++dz)
#pragma unroll
        for (int dy = -1; dy <= 1; ++dy)
#pragma unroll
            for (int dx = -1; dx <= 1; ++dx) {
                int nz = z + dz, ny = y + dy, nx = x + dx;
                bool inb = (unsigned)nz < 64u && (unsigned)ny < 128u && (unsigned)nx < 128u;
                float In = inb ? img[g + dz * 16384 + dy * 128 + dx] : 0.f;
                float dd = Ic - In;
                float w = Sc[dz * dz + dy * dy + dx * dx] * __expf(-2.f * dd * dd);
                den += w;
                numi += inb ? w : 0.f;
                rec[o * 4] = (hf)w;
                ++o;
            }
    float dq = h1 - h0;
    qA[g] = 1.f / (1.f + __expf(-dq));                 // q after softmax(logits)
    M[g]  = Bc / den;
    P[g]  = dq * t - Ksp * bones - Kbl * (numi / den);
}

__device__ __forceinline__ void ldrow(const float* p, float* r) {
    float4 a = *(const float4*)p;
    float4 b = *(const float4*)(p + 4);
    r[0] = a.x; r[1] = a.y; r[2] = a.z; r[3] = a.w;
    r[4] = b.x; r[5] = b.y; r[6] = b.z; r[7] = b.w;
}

// Tile: 8(z) x 8(y) x 16(x) outputs per block, 256 threads, 4 x-voxels/thread.
template <bool LAST>
__global__ __launch_bounds__(256) void crf_iter(
    const float* __restrict__ qsrc, float* __restrict__ qdst,
    const float* __restrict__ P, const float* __restrict__ M,
    const hf* __restrict__ W,
    const float* __restrict__ sw, const float* __restrict__ cm,
    const float* __restrict__ f1, float* __restrict__ out)
{
    const float K0 = 0.05448868f, K1 = 0.24420134f, K2 = 0.40261995f;

    __shared__ float qs[12][12][20];   // q tile, halo 2
    __shared__ float t1[12][12][16];   // blur-x
    __shared__ float t2[12][8][16];    // blur-xy

    const int tid = threadIdx.x;
    const int x0 = blockIdx.x * 16, y0 = blockIdx.y * 8, zB = blockIdx.z * 8;

    const float cd0 = cm[2] - cm[0], cd1 = cm[3] - cm[1];
    const float Ac = cd0 * (sw[1] - sw[0]) + cd1 * (sw[3] - sw[2]);

    float* qf = &qs[0][0][0];
    for (int idx = tid; idx < 2880; idx += 256) {
        int lz = idx / 240, r = idx - lz * 240, ly = r / 20, lx2 = r - ly * 20;
        int gz = zB + lz - 2, gy = y0 + ly - 2, gx = x0 + lx2 - 2;
        float v = 0.f;
        if ((unsigned)gz < 64u && (unsigned)gy < 128u && (unsigned)gx < 128u)
            v = qsrc[(gz << 14) + (gy << 7) + gx];
        qf[idx] = v;
    }
    __syncthreads();

    // blur along x
    for (int idx = tid; idx < 576; idx += 256) {
        int lz = idx / 48, r = idx - lz * 48, ly = r / 4, c4 = (r - ly * 4) * 4;
        const float* row = &qs[lz][ly][c4];
        float4 a = *(const float4*)row;
        float4 b = *(const float4*)(row + 4);
        float4 o;
        o.x = K0 * (a.x + b.x) + K1 * (a.y + a.w) + K2 * a.z;
        o.y = K0 * (a.y + b.y) + K1 * (a.z + b.x) + K2 * a.w;
        o.z = K0 * (a.z + b.z) + K1 * (a.w + b.y) + K2 * b.x;
        o.w = K0 * (a.w + b.w) + K1 * (b.x + b.z) + K2 * b.y;
        *(float4*)&t1[lz][ly][c4] = o;
    }
    __syncthreads();

    // blur along y
    for (int idx = tid; idx < 384; idx += 256) {
        int lz = idx / 32, r = idx - lz * 32, ly = r / 4, c4 = (r - ly * 4) * 4;
        float4 r0 = *(const float4*)&t1[lz][ly][c4];
        float4 r1 = *(const float4*)&t1[lz][ly + 1][c4];
        float4 r2 = *(const float4*)&t1[lz][ly + 2][c4];
        float4 r3 = *(const float4*)&t1[lz][ly + 3][c4];
        float4 r4 = *(const float4*)&t1[lz][ly + 4][c4];
        float4 o;
        o.x = K0 * (r0.x + r4.x) + K1 * (r1.x + r3.x) + K2 * r2.x;
        o.y = K0 * (r0.y + r4.y) + K1 * (r1.y + r3.y) + K2 * r2.y;
        o.z = K0 * (r0.z + r4.z) + K1 * (r1.z + r3.z) + K2 * r2.z;
        o.w = K0 * (r0.w + r4.w) + K1 * (r1.w + r3.w) + K2 * r2.w;
        *(float4*)&t2[lz][ly][c4] = o;
    }
    __syncthreads();

    const int lx = (tid & 3) * 4;
    const int ly = (tid >> 2) & 7;
    const int lz = tid >> 5;

    // blur along z (final spatial message)
    float4 za = *(const float4*)&t2[lz][ly][lx];
    float4 zb = *(const float4*)&t2[lz + 1][ly][lx];
    float4 zc = *(const float4*)&t2[lz + 2][ly][lx];
    float4 zd = *(const float4*)&t2[lz + 3][ly][lx];
    float4 ze = *(const float4*)&t2[lz + 4][ly][lx];
    float sp[4];
    sp[0] = K0 * (za.x + ze.x) + K1 * (zb.x + zd.x) + K2 * zc.x;
    sp[1] = K0 * (za.y + ze.y) + K1 * (zb.y + zd.y) + K2 * zc.y;
    sp[2] = K0 * (za.z + ze.z) + K1 * (zb.z + zd.z) + K2 * zc.z;
    sp[3] = K0 * (za.w + ze.w) + K1 * (zb.w + zd.w) + K2 * zc.w;

    const int g = ((zB + lz) << 14) + ((y0 + ly) << 7) + (x0 + lx);

    // bilateral: 27 dirs, all weights at center record (contiguous 216 B)
    const hf* rec = W + (g >> 2) * RSTRIDE;
    float num[4] = {0.f, 0.f, 0.f, 0.f};
    float qrow[8];
#pragma unroll
    for (int r = 0; r < 9; ++r) {
        const int dz = r / 3 - 1, dy = r % 3 - 1;
        ldrow(&qs[lz + 2 + dz][ly + 2 + dy][lx], qrow);
        hf4 w0 = *(const hf4*)(rec + r * 12);
        hf4 w1 = *(const hf4*)(rec + r * 12 + 4);
        hf4 w2 = *(const hf4*)(rec + r * 12 + 8);
#pragma unroll
        for (int xi = 0; xi < 4; ++xi)
            num[xi] += (float)w0[xi] * qrow[1 + xi]
                     + (float)w1[xi] * qrow[2 + xi]
                     + (float)w2[xi] * qrow[3 + xi];
    }

    float4 Pv = *(const float4*)&P[g];
    float4 Mv = *(const float4*)&M[g];
    float pr[4] = {Pv.x, Pv.y, Pv.z, Pv.w};
    float mv[4] = {Mv.x, Mv.y, Mv.z, Mv.w};
    float qn[4];
#pragma unroll
    for (int xi = 0; xi < 4; ++xi) {
        float dn = pr[xi] - Ac * sp[xi] - mv[xi] * num[xi];
        qn[xi] = 1.f / (1.f + __expf(-dn));
    }

    if (!LAST) {
        float4 o = {qn[0], qn[1], qn[2], qn[3]};
        *(float4*)&qdst[g] = o;
    } else {
        float4 o1 = {qn[0], qn[1], qn[2], qn[3]};
        float4 o0 = {1.f - qn[0], 1.f - qn[1], 1.f - qn[2], 1.f - qn[3]};
        *(float4*)&out[g] = o0;
        *(float4*)&out[NN + g] = o1;
        float4 fv = *(const float4*)&f1[g];
        *(float4*)&out[2 * NN + g] = fv;
    }
}

extern "C" void kernel_launch(void* const* d_in, const int* in_sizes, int n_in,
                              void* d_out, int out_size, void* d_ws, size_t ws_size,
                              hipStream_t stream)
{
    const float* img = (const float*)d_in[0];
    const float* h   = (const float*)d_in[1];
    const float* f1  = (const float*)d_in[2];
    const float* w0  = (const float*)d_in[3];
    const float* sw  = (const float*)d_in[4];
    const float* bw  = (const float*)d_in[5];
    const float* cm  = (const float*)d_in[6];
    float* out = (float*)d_out;

    float* qA = (float*)d_ws;
    float* qB = qA + (NN + PAD);
    float* P  = qB + (NN + PAD);
    float* M  = P + (NN + PAD);
    hf* W = (hf*)(M + (NN + PAD));   // AoS records, 58.7 MB

    crf_pre<<<NN / 256, 256, 0, stream>>>(img, h, f1, w0, sw, bw, cm, qA, P, M, W);

    dim3 grid(WW / 16, HH / 8, DD / 8);   // 1024 blocks
    crf_iter<false><<<grid, 256, 0, stream>>>(qA, qB, P, M, W, sw, cm, nullptr, nullptr);
    crf_iter<false><<<grid, 256, 0, stream>>>(qB, qA, P, M, W, sw, cm, nullptr, nullptr);
    crf_iter<false><<<grid, 256, 0, stream>>>(qA, qB, P, M, W, sw, cm, nullptr, nullptr);
    crf_iter<false><<<grid, 256, 0, stream>>>(qB, qA, P, M, W, sw, cm, nullptr, nullptr);
    crf_iter<true ><<<grid, 256, 0, stream>>>(qA, nullptr, P, M, W, sw, cm, f1, out);
}

// Round 6
// 161.540 us; speedup vs baseline: 1.6665x; 1.4746x over previous
//
#include <hip/hip_runtime.h>

// DenseCRF-RNN fwd, D=64,H=128,W=128, L=2, 5 iters.
// 2-label reduction: track q1 = sigmoid(cur1-cur0) only.
// Per iter: delta = P - Ac*blur3d(q) - M*num(q),  q_new = sigmoid(delta)
//   num(q) = sum_{27 dirs o} w255_o(x) * q(x+d_o)   (u8 weights, 255-scaled)
//   M = Bc/(den*255),  P = dU - Ksp*blurOnes - Kbl*bilatOnes (img-only, once).
// R3: fp16 planes @2MiB stride -> L2 set thrash. R5: AoS 224-B records ->
//   2.6x write amp in pre + L1 thrash on read (224 lines/wave).
// R6: W[tile][o][tid][4vox] u8 -- pre uses the SAME tile geometry as iter, so
//   both the o-plane store (pre) and load (iter) are one u32/lane = 256-B
//   contiguous per wave. Traffic halved (u8), M absorbs Bc/(den*255).
// ws: qA | qB | P | M (f32, NN+264 floats apart) | W u8 28.3 MB  (~45 MB).

#define DD 64
#define HH 128
#define WW 128
#define NN (DD*HH*WW)   // 1048576
#define PAD 264
#define TILE_WU 6912    // u32 per tile weight block: 27 * 256

__device__ __forceinline__ float bfac(int p, int dim) {
    const float K[5] = {0.05448868f, 0.24420134f, 0.40261995f, 0.24420134f, 0.05448868f};
    float s = 0.f;
#pragma unroll
    for (int o = -2; o <= 2; ++o) {
        int pp = p + o;
        s += (pp >= 0 && pp < dim) ? K[o + 2] : 0.f;
    }
    return s;
}

__device__ __forceinline__ void ldrow(const float* p, float* r) {
    float4 a = *(const float4*)p;
    float4 b = *(const float4*)(p + 4);
    r[0] = a.x; r[1] = a.y; r[2] = a.z; r[3] = a.w;
    r[4] = b.x; r[5] = b.y; r[6] = b.z; r[7] = b.w;
}

// Tile 8(z) x 8(y) x 16(x), 256 threads, 4 x-voxels/thread (same as crf_iter).
__global__ __launch_bounds__(256) void crf_pre(
    const float* __restrict__ img, const float* __restrict__ h,
    const float* __restrict__ f1, const float* __restrict__ w0,
    const float* __restrict__ sw, const float* __restrict__ bw,
    const float* __restrict__ cm,
    float* __restrict__ qA, float* __restrict__ P,
    float* __restrict__ M, unsigned int* __restrict__ W)
{
    const float Sc[4] = {1.f, 0.80073740f, 0.64118039f, 0.51341712f};
    __shared__ float ims[10][10][20];   // img tile, halo 1 (x uses 18 of 20)

    const int tid = threadIdx.x;
    const int x0 = blockIdx.x * 16, y0 = blockIdx.y * 8, z0 = blockIdx.z * 8;
    const int T = ((int)blockIdx.z * 16 + (int)blockIdx.y) * 8 + (int)blockIdx.x;

    float* imf = &ims[0][0][0];
    for (int idx = tid; idx < 2000; idx += 256) {
        int lz2 = idx / 200, r = idx - lz2 * 200, ly2 = r / 20, lx2 = r - ly2 * 20;
        int gz = z0 + lz2 - 1, gy = y0 + ly2 - 1, gx = x0 + lx2 - 1;
        float v = 0.f;
        if ((unsigned)gz < 64u && (unsigned)gy < 128u && (unsigned)gx < 128u)
            v = img[(gz << 14) + (gy << 7) + gx];
        imf[idx] = v;
    }
    __syncthreads();

    const int lx = (tid & 3) * 4;
    const int ly = (tid >> 2) & 7;
    const int lz = tid >> 5;
    const int x = x0 + lx, y = y0 + ly, z = z0 + lz;
    const int g = (z << 14) + (y << 7) + x;

    const float cd0 = cm[2] - cm[0], cd1 = cm[3] - cm[1];
    const float Ksp = cd0 * sw[0] + cd1 * sw[2];
    const float Kbl = cd0 * bw[0] + cd1 * bw[2];
    const float Bc  = cd0 * (bw[1] - bw[0]) + cd1 * (bw[3] - bw[2]);

    float rowC[8];
    ldrow(&ims[lz + 1][ly + 1][lx], rowC);
    const float Ic[4] = {rowC[1], rowC[2], rowC[3], rowC[4]};

    float den[4] = {0.f, 0.f, 0.f, 0.f}, numi[4] = {0.f, 0.f, 0.f, 0.f};
    unsigned int* __restrict__ Wt = W + T * TILE_WU;

    float rI[8];
#pragma unroll
    for (int r9 = 0; r9 < 9; ++r9) {
        const int dz = r9 / 3 - 1, dy = r9 % 3 - 1;
        ldrow(&ims[lz + 1 + dz][ly + 1 + dy][lx], rI);
        const bool zyin = ((unsigned)(z + dz) < 64u) && ((unsigned)(y + dy) < 128u);
#pragma unroll
        for (int c = 0; c < 3; ++c) {
            const int dx = c - 1;
            const float s = Sc[dz * dz + dy * dy + dx * dx];
            unsigned pack = 0;
#pragma unroll
            for (int xi = 0; xi < 4; ++xi) {
                float dd = Ic[xi] - rI[xi + c];
                float w = s * __expf(-2.f * dd * dd);
                den[xi] += w;
                bool inb = zyin && ((unsigned)(x + xi + dx) < 128u);
                numi[xi] += inb ? w : 0.f;
                pack |= ((unsigned)(w * 255.f + 0.5f)) << (8 * xi);
            }
            Wt[(r9 * 3 + c) * 256 + tid] = pack;   // 256-B contiguous per wave
        }
    }

    float4 h0v = *(const float4*)&h[g];
    float4 h1v = *(const float4*)&h[NN + g];
    float4 f1v = *(const float4*)&f1[g];
    const float w00 = w0[0];
    const float bz = bfac(z, 64), by = bfac(y, 128);
    float hh0[4] = {h0v.x, h0v.y, h0v.z, h0v.w};
    float hh1[4] = {h1v.x, h1v.y, h1v.z, h1v.w};
    float ff[4]  = {f1v.x, f1v.y, f1v.z, f1v.w};
    float qv[4], Pv[4], Mv[4];
#pragma unroll
    for (int xi = 0; xi < 4; ++xi) {
        float dq = hh1[xi] - hh0[xi];
        float logp = -0.5f * Ic[xi] * Ic[xi] - 0.91893853320467274f;
        float t = -(w00 + logp - ff[xi]);
        float bones = bz * by * bfac(x + xi, 128);
        qv[xi] = 1.f / (1.f + __expf(-dq));
        Pv[xi] = dq * t - Ksp * bones - Kbl * (numi[xi] / den[xi]);
        Mv[xi] = Bc / (den[xi] * 255.f);
    }
    *(float4*)&qA[g] = {qv[0], qv[1], qv[2], qv[3]};
    *(float4*)&P[g]  = {Pv[0], Pv[1], Pv[2], Pv[3]};
    *(float4*)&M[g]  = {Mv[0], Mv[1], Mv[2], Mv[3]};
}

// Tile: 8(z) x 8(y) x 16(x) outputs per block, 256 threads, 4 x-voxels/thread.
template <bool LAST>
__global__ __launch_bounds__(256) void crf_iter(
    const float* __restrict__ qsrc, float* __restrict__ qdst,
    const float* __restrict__ P, const float* __restrict__ M,
    const unsigned int* __restrict__ W,
    const float* __restrict__ sw, const float* __restrict__ cm,
    const float* __restrict__ f1, float* __restrict__ out)
{
    const float K0 = 0.05448868f, K1 = 0.24420134f, K2 = 0.40261995f;

    __shared__ float qs[12][12][20];   // q tile, halo 2
    __shared__ float t1[12][12][16];   // blur-x
    __shared__ float t2[12][8][16];    // blur-xy

    const int tid = threadIdx.x;
    const int x0 = blockIdx.x * 16, y0 = blockIdx.y * 8, zB = blockIdx.z * 8;
    const int T = ((int)blockIdx.z * 16 + (int)blockIdx.y) * 8 + (int)blockIdx.x;

    const float cd0 = cm[2] - cm[0], cd1 = cm[3] - cm[1];
    const float Ac = cd0 * (sw[1] - sw[0]) + cd1 * (sw[3] - sw[2]);

    float* qf = &qs[0][0][0];
    for (int idx = tid; idx < 2880; idx += 256) {
        int lz2 = idx / 240, r = idx - lz2 * 240, ly2 = r / 20, lx2 = r - ly2 * 20;
        int gz = zB + lz2 - 2, gy = y0 + ly2 - 2, gx = x0 + lx2 - 2;
        float v = 0.f;
        if ((unsigned)gz < 64u && (unsigned)gy < 128u && (unsigned)gx < 128u)
            v = qsrc[(gz << 14) + (gy << 7) + gx];
        qf[idx] = v;
    }
    __syncthreads();

    // blur along x
    for (int idx = tid; idx < 576; idx += 256) {
        int lz2 = idx / 48, r = idx - lz2 * 48, ly2 = r / 4, c4 = (r - ly2 * 4) * 4;
        const float* row = &qs[lz2][ly2][c4];
        float4 a = *(const float4*)row;
        float4 b = *(const float4*)(row + 4);
        float4 o;
        o.x = K0 * (a.x + b.x) + K1 * (a.y + a.w) + K2 * a.z;
        o.y = K0 * (a.y + b.y) + K1 * (a.z + b.x) + K2 * a.w;
        o.z = K0 * (a.z + b.z) + K1 * (a.w + b.y) + K2 * b.x;
        o.w = K0 * (a.w + b.w) + K1 * (b.x + b.z) + K2 * b.y;
        *(float4*)&t1[lz2][ly2][c4] = o;
    }
    __syncthreads();

    // blur along y
    for (int idx = tid; idx < 384; idx += 256) {
        int lz2 = idx / 32, r = idx - lz2 * 32, ly2 = r / 4, c4 = (r - ly2 * 4) * 4;
        float4 r0 = *(const float4*)&t1[lz2][ly2][c4];
        float4 r1 = *(const float4*)&t1[lz2][ly2 + 1][c4];
        float4 r2 = *(const float4*)&t1[lz2][ly2 + 2][c4];
        float4 r3 = *(const float4*)&t1[lz2][ly2 + 3][c4];
        float4 r4 = *(const float4*)&t1[lz2][ly2 + 4][c4];
        float4 o;
        o.x = K0 * (r0.x + r4.x) + K1 * (r1.x + r3.x) + K2 * r2.x;
        o.y = K0 * (r0.y + r4.y) + K1 * (r1.y + r3.y) + K2 * r2.y;
        o.z = K0 * (r0.z + r4.z) + K1 * (r1.z + r3.z) + K2 * r2.z;
        o.w = K0 * (r0.w + r4.w) + K1 * (r1.w + r3.w) + K2 * r2.w;
        *(float4*)&t2[lz2][ly2][c4] = o;
    }
    __syncthreads();

    const int lx = (tid & 3) * 4;
    const int ly = (tid >> 2) & 7;
    const int lz = tid >> 5;

    // blur along z (final spatial message)
    float4 za = *(const float4*)&t2[lz][ly][lx];
    float4 zb = *(const float4*)&t2[lz + 1][ly][lx];
    float4 zc = *(const float4*)&t2[lz + 2][ly][lx];
    float4 zd = *(const float4*)&t2[lz + 3][ly][lx];
    float4 ze = *(const float4*)&t2[lz + 4][ly][lx];
    float sp[4];
    sp[0] = K0 * (za.x + ze.x) + K1 * (zb.x + zd.x) + K2 * zc.x;
    sp[1] = K0 * (za.y + ze.y) + K1 * (zb.y + zd.y) + K2 * zc.y;
    sp[2] = K0 * (za.z + ze.z) + K1 * (zb.z + zd.z) + K2 * zc.z;
    sp[3] = K0 * (za.w + ze.w) + K1 * (zb.w + zd.w) + K2 * zc.w;

    const int g = ((zB + lz) << 14) + ((y0 + ly) << 7) + (x0 + lx);

    // bilateral: 27 dirs, u8 weights, one coalesced u32/lane per dir-plane
    const unsigned int* __restrict__ Wt = W + T * TILE_WU;
    float num[4] = {0.f, 0.f, 0.f, 0.f};
    float qrow[8];
#pragma unroll
    for (int r9 = 0; r9 < 9; ++r9) {
        const int dz = r9 / 3 - 1, dy = r9 % 3 - 1;
        ldrow(&qs[lz + 2 + dz][ly + 2 + dy][lx], qrow);
#pragma unroll
        for (int c = 0; c < 3; ++c) {
            unsigned wv = Wt[(r9 * 3 + c) * 256 + tid];
#pragma unroll
            for (int xi = 0; xi < 4; ++xi)
                num[xi] += (float)((wv >> (8 * xi)) & 0xffu) * qrow[xi + 1 + c];
        }
    }

    float4 Pv = *(const float4*)&P[g];
    float4 Mv = *(const float4*)&M[g];
    float pr[4] = {Pv.x, Pv.y, Pv.z, Pv.w};
    float mv[4] = {Mv.x, Mv.y, Mv.z, Mv.w};
    float qn[4];
#pragma unroll
    for (int xi = 0; xi < 4; ++xi) {
        float dn = pr[xi] - Ac * sp[xi] - mv[xi] * num[xi];
        qn[xi] = 1.f / (1.f + __expf(-dn));
    }

    if (!LAST) {
        float4 o = {qn[0], qn[1], qn[2], qn[3]};
        *(float4*)&qdst[g] = o;
    } else {
        float4 o1 = {qn[0], qn[1], qn[2], qn[3]};
        float4 o0 = {1.f - qn[0], 1.f - qn[1], 1.f - qn[2], 1.f - qn[3]};
        *(float4*)&out[g] = o0;
        *(float4*)&out[NN + g] = o1;
        float4 fv = *(const float4*)&f1[g];
        *(float4*)&out[2 * NN + g] = fv;
    }
}

extern "C" void kernel_launch(void* const* d_in, const int* in_sizes, int n_in,
                              void* d_out, int out_size, void* d_ws, size_t ws_size,
                              hipStream_t stream)
{
    const float* img = (const float*)d_in[0];
    const float* h   = (const float*)d_in[1];
    const float* f1  = (const float*)d_in[2];
    const float* w0  = (const float*)d_in[3];
    const float* sw  = (const float*)d_in[4];
    const float* bw  = (const float*)d_in[5];
    const float* cm  = (const float*)d_in[6];
    float* out = (float*)d_out;

    float* qA = (float*)d_ws;
    float* qB = qA + (NN + PAD);
    float* P  = qB + (NN + PAD);
    float* M  = P + (NN + PAD);
    unsigned int* W = (unsigned int*)(M + (NN + PAD));   // u8 weights, 28.3 MB

    dim3 grid(WW / 16, HH / 8, DD / 8);   // 1024 blocks, shared by pre & iter
    crf_pre<<<grid, 256, 0, stream>>>(img, h, f1, w0, sw, bw, cm, qA, P, M, W);

    crf_iter<false><<<grid, 256, 0, stream>>>(qA, qB, P, M, W, sw, cm, nullptr, nullptr);
    crf_iter<false><<<grid, 256, 0, stream>>>(qB, qA, P, M, W, sw, cm, nullptr, nullptr);
    crf_iter<false><<<grid, 256, 0, stream>>>(qA, qB, P, M, W, sw, cm, nullptr, nullptr);
    crf_iter<false><<<grid, 256, 0, stream>>>(qB, qA, P, M, W, sw, cm, nullptr, nullptr);
    crf_iter<true ><<<grid, 256, 0, stream>>>(qA, nullptr, P, M, W, sw, cm, f1, out);
}